// Round 6
// baseline (382.291 us; speedup 1.0000x reference)
//
#include <hip/hip_runtime.h>
#include <hip/hip_bf16.h>

#define NN 6144
#define INPUT 1024
#define HID 256

using frag  = __attribute__((ext_vector_type(8))) short;   // 8 bf16
using f32x4 = __attribute__((ext_vector_type(4))) float;

typedef __attribute__((address_space(3))) unsigned int lds_u32;
typedef const __attribute__((address_space(1))) unsigned int glb_u32;

// async global->LDS DMA: each lane of the wave moves 16B from its own global
// address to (wave-uniform lds base) + lane*16. Drained by __syncthreads().
static __device__ __forceinline__ void dma16(const void* g, void* l) {
    __builtin_amdgcn_global_load_lds((glb_u32*)g, (lds_u32*)l, 16, 0, 0);
}

static __device__ __forceinline__ unsigned short bf16u(float x) {
    unsigned u = __float_as_uint(x);
    u += 0x7fff + ((u >> 16) & 1);     // RNE
    return (unsigned short)(u >> 16);
}

// ---------------- convert X -> bf16 row-major ----------------
__global__ __launch_bounds__(256) void k_convert_x(const float* __restrict__ X,
                                                   unsigned short* __restrict__ Xb) {
    int t = blockIdx.x * 256 + threadIdx.x;
    float4 v = reinterpret_cast<const float4*>(X)[t];
    ushort4 o;
    o.x = bf16u(v.x); o.y = bf16u(v.y); o.z = bf16u(v.z); o.w = bf16u(v.w);
    reinterpret_cast<ushort4*>(Xb)[t] = o;
}

// ---------------- convert W -> Wt bf16 transposed [HID][INPUT] ----------------
__global__ __launch_bounds__(256) void k_convert_w(const float* __restrict__ W,
                                                   unsigned short* __restrict__ Wt) {
    int t = blockIdx.x * 256 + threadIdx.x;          // t = n*1024 + k
    int n = t >> 10, k = t & 1023;
    Wt[t] = bf16u(W[k * HID + n]);
}

// ---------------- GEMM1: hT = (Xb @ W)^T bf16 + fused s1/s2 ----------------
// m97-style: DMA-stage A(Xb) and B(Wt) tiles to LDS in fragment order, 2 barriers
// per 128-K chunk. Block 128 thr = 2 waves; M=32 (wave w: rows i0+w*16..+15),
// N=64 (4 B-frags); grid (192,4); K=1024 -> 8 chunks.
__global__ __launch_bounds__(128) void k_gemm1(const unsigned short* __restrict__ Xb,
                                               const unsigned short* __restrict__ Wt,
                                               const float* __restrict__ a_edge,
                                               unsigned short* __restrict__ hT,
                                               float* __restrict__ s1,
                                               float* __restrict__ s2) {
    __shared__ unsigned short As[8 * 512];    // frag f = kk*2+w   (1KB each)
    __shared__ unsigned short Bs[16 * 512];   // frag f = kk*4+ng
    int t = threadIdx.x, w = t >> 6, l = t & 63, lm = l & 15, q = l >> 4;
    int i0 = blockIdx.x * 32, n0 = blockIdx.y * 64;

    const unsigned short* ga  = Xb + (size_t)(i0 + w * 16 + lm) * INPUT + q * 8;
    const unsigned short* gb0 = Wt + (size_t)(n0 + (2 * w) * 16 + lm) * INPUT + q * 8;
    const unsigned short* gb1 = gb0 + 16 * INPUT;

    f32x4 acc[4] = {};

    for (int c = 0; c < 8; c++) {
        int jc = c * 128;
        if (c) __syncthreads();                 // previous consume done before overwrite
#pragma unroll
        for (int kk = 0; kk < 4; kk++) {
            dma16(ga + jc + kk * 32, &As[(kk * 2 + w) * 512]);
            dma16(gb0 + jc + kk * 32, &Bs[(kk * 4 + 2 * w) * 512]);
            dma16(gb1 + jc + kk * 32, &Bs[(kk * 4 + 2 * w + 1) * 512]);
        }
        __syncthreads();                        // drains DMA (vmcnt0) + publishes LDS
#pragma unroll
        for (int kk = 0; kk < 4; kk++) {
            frag a = *reinterpret_cast<const frag*>(&As[(kk * 2 + w) * 512 + l * 8]);
#pragma unroll
            for (int nt = 0; nt < 4; nt++) {
                frag b = *reinterpret_cast<const frag*>(&Bs[(kk * 4 + nt) * 512 + l * 8]);
                acc[nt] = __builtin_amdgcn_mfma_f32_16x16x32_bf16(a, b, acc[nt], 0, 0, 0);
            }
        }
    }

    // hT write: C/D layout col=lm (n within frag), row=q*4+r
#pragma unroll
    for (int nt = 0; nt < 4; nt++) {
        ushort4 o;
        o.x = bf16u(acc[nt][0]); o.y = bf16u(acc[nt][1]);
        o.z = bf16u(acc[nt][2]); o.w = bf16u(acc[nt][3]);
        *reinterpret_cast<ushort4*>(hT + (size_t)(n0 + nt * 16 + lm) * NN + i0 + w * 16 + q * 4) = o;
    }

    // fused s1/s2 partials over this block's 64 n
    float a1v0 = a_edge[n0 + lm],            a1v1 = a_edge[n0 + 16 + lm];
    float a1v2 = a_edge[n0 + 32 + lm],       a1v3 = a_edge[n0 + 48 + lm];
    float a2v0 = a_edge[HID + n0 + lm],      a2v1 = a_edge[HID + n0 + 16 + lm];
    float a2v2 = a_edge[HID + n0 + 32 + lm], a2v3 = a_edge[HID + n0 + 48 + lm];
#pragma unroll
    for (int r = 0; r < 4; r++) {
        float v1 = acc[0][r] * a1v0 + acc[1][r] * a1v1 + acc[2][r] * a1v2 + acc[3][r] * a1v3;
        float v2 = acc[0][r] * a2v0 + acc[1][r] * a2v1 + acc[2][r] * a2v2 + acc[3][r] * a2v3;
        v1 += __shfl_xor(v1, 1); v2 += __shfl_xor(v2, 1);
        v1 += __shfl_xor(v1, 2); v2 += __shfl_xor(v2, 2);
        v1 += __shfl_xor(v1, 4); v2 += __shfl_xor(v2, 4);
        v1 += __shfl_xor(v1, 8); v2 += __shfl_xor(v2, 8);
        if (lm == 0) {
            atomicAdd(&s1[i0 + w * 16 + q * 4 + r], v1);
            atomicAdd(&s2[i0 + w * 16 + q * 4 + r], v2);
        }
    }
}

// ---------------- k_build: P strip = exp(leaky(s1+s2)) masked, + denom row-sums ----------------
// One block per row i; strip cols [j0, j0+Kstrip). Coalesced stream, no hot-loop barriers.
__global__ __launch_bounds__(256) void k_build(const int* __restrict__ adj,
                                               const float* __restrict__ s1,
                                               const float* __restrict__ s2,
                                               unsigned short* __restrict__ P,
                                               float* __restrict__ denom,
                                               int j0, int Kstrip) {
    __shared__ float red[4];
    int i = blockIdx.x, t = threadIdx.x;
    float s1v = s1[i];
    const int* ar = adj + (size_t)i * NN + j0;
    const float* sp = s2 + j0;
    unsigned short* pr = P + (size_t)i * Kstrip;
    float dsum = 0.f;

    for (int seg = 0; seg < Kstrip; seg += 1024) {
        int c = seg + t * 4;
        int4   av = *reinterpret_cast<const int4*>(ar + c);
        float4 sv = *reinterpret_cast<const float4*>(sp + c);
        float sc, e, p0, p1, p2, p3;
        sc = s1v + sv.x; e = __expf(fmaxf(sc, 0.2f * sc)); p0 = av.x ? e : 0.f;
        sc = s1v + sv.y; e = __expf(fmaxf(sc, 0.2f * sc)); p1 = av.y ? e : 0.f;
        sc = s1v + sv.z; e = __expf(fmaxf(sc, 0.2f * sc)); p2 = av.z ? e : 0.f;
        sc = s1v + sv.w; e = __expf(fmaxf(sc, 0.2f * sc)); p3 = av.w ? e : 0.f;
        dsum += (p0 + p1) + (p2 + p3);
        ushort4 o;
        o.x = bf16u(p0); o.y = bf16u(p1); o.z = bf16u(p2); o.w = bf16u(p3);
        *reinterpret_cast<ushort4*>(pr + c) = o;
    }

    dsum += __shfl_xor(dsum, 1);  dsum += __shfl_xor(dsum, 2);
    dsum += __shfl_xor(dsum, 4);  dsum += __shfl_xor(dsum, 8);
    dsum += __shfl_xor(dsum, 16); dsum += __shfl_xor(dsum, 32);
    if ((t & 63) == 0) red[t >> 6] = dsum;
    __syncthreads();
    if (t == 0) denom[i] += red[0] + red[1] + red[2] + red[3];   // strip-serial accumulate
}

// ---------------- k_gemm2: U += P_strip @ h  (m97-style DMA-staged MFMA GEMM) ----------------
// Block 128 thr = 2 waves; M=32, N=64; grid (192,4); K=Kstrip in chunks of 128.
// A = P strip (stride Kstrip), B = hT (stride NN, cols offset j0g). U read-add-write
// (strips are stream-serial; one block per (i,n) tile -> race-free).
__global__ __launch_bounds__(128) void k_gemm2(const unsigned short* __restrict__ Pst,
                                               const unsigned short* __restrict__ hT,
                                               float* __restrict__ U,
                                               int j0g, int Kstrip) {
    __shared__ unsigned short As[8 * 512];
    __shared__ unsigned short Bs[16 * 512];
    int t = threadIdx.x, w = t >> 6, l = t & 63, lm = l & 15, q = l >> 4;
    int i0 = blockIdx.x * 32, n0 = blockIdx.y * 64;

    const unsigned short* ga  = Pst + (size_t)(i0 + w * 16 + lm) * Kstrip + q * 8;
    const unsigned short* gb0 = hT + (size_t)(n0 + (2 * w) * 16 + lm) * NN + j0g + q * 8;
    const unsigned short* gb1 = gb0 + 16 * NN;

    f32x4 acc[4] = {};
    int nchunk = Kstrip >> 7;

    for (int c = 0; c < nchunk; c++) {
        int jc = c * 128;
        if (c) __syncthreads();
#pragma unroll
        for (int kk = 0; kk < 4; kk++) {
            dma16(ga + jc + kk * 32, &As[(kk * 2 + w) * 512]);
            dma16(gb0 + jc + kk * 32, &Bs[(kk * 4 + 2 * w) * 512]);
            dma16(gb1 + jc + kk * 32, &Bs[(kk * 4 + 2 * w + 1) * 512]);
        }
        __syncthreads();
#pragma unroll
        for (int kk = 0; kk < 4; kk++) {
            frag a = *reinterpret_cast<const frag*>(&As[(kk * 2 + w) * 512 + l * 8]);
#pragma unroll
            for (int nt = 0; nt < 4; nt++) {
                frag b = *reinterpret_cast<const frag*>(&Bs[(kk * 4 + nt) * 512 + l * 8]);
                acc[nt] = __builtin_amdgcn_mfma_f32_16x16x32_bf16(a, b, acc[nt], 0, 0, 0);
            }
        }
    }

    int ib = i0 + w * 16 + q * 4;
#pragma unroll
    for (int nt = 0; nt < 4; nt++)
#pragma unroll
        for (int r = 0; r < 4; r++) {
            size_t off = (size_t)(ib + r) * HID + n0 + nt * 16 + lm;
            U[off] += acc[nt][r];
        }
}

// ---------------- normalize ----------------
__global__ __launch_bounds__(256) void k_norm(const float* __restrict__ U,
                                              const float* __restrict__ denom,
                                              float* __restrict__ out) {
    int i = blockIdx.x, t = threadIdx.x;
    float d = denom[i];
    float u = U[(size_t)i * HID + t];
    out[(size_t)i * HID + t] = (d != 0.f) ? u / d : 0.f;
}

extern "C" void kernel_launch(void* const* d_in, const int* in_sizes, int n_in,
                              void* d_out, int out_size, void* d_ws, size_t ws_size,
                              hipStream_t stream) {
    const float* X      = (const float*)d_in[0];   // 6144x1024
    const float* W      = (const float*)d_in[1];   // 1024x256
    const float* a_edge = (const float*)d_in[2];   // 512
    const int*   adj    = (const int*)d_in[3];     // 6144x6144
    float* out = (float*)d_out;

    // workspace layout
    float* U     = (float*)d_ws;                         // NN*HID f32 (6.3 MB)
    float* denom = U + (size_t)NN * HID;                 // NN
    float* s1    = denom + NN;                           // NN
    float* s2    = s1 + NN;                              // NN
    unsigned short* hT = (unsigned short*)(s2 + NN);     // HID*NN bf16 (3.1 MB)
    unsigned short* Xb = hT + (size_t)HID * NN;          // NN*INPUT bf16 (12.6 MB)
    unsigned short* Wt = Xb + (size_t)NN * INPUT;        // HID*INPUT bf16 (0.5 MB)
    unsigned short* P  = Wt + (size_t)HID * INPUT;       // NN*Kstrip bf16

    size_t fixedB = ((size_t)NN * HID + 3 * NN) * sizeof(float)
                  + ((size_t)HID * NN + (size_t)NN * INPUT + (size_t)HID * INPUT) * 2;
    // strips: Kstrip must be a multiple of 1024 (k_build) and 128 (gemm2)
    int ns = 6;
    if (fixedB + (size_t)NN * NN * 2 <= ws_size) ns = 1;
    else if (fixedB + (size_t)NN * (NN / 2) * 2 <= ws_size) ns = 2;
    else if (fixedB + (size_t)NN * (NN / 3) * 2 <= ws_size) ns = 3;
    int Kstrip = NN / ns;

    hipMemsetAsync(U, 0, ((size_t)NN * HID + 3 * NN) * sizeof(float), stream);
    k_convert_x<<<NN * INPUT / 1024, 256, 0, stream>>>(X, Xb);
    k_convert_w<<<INPUT * HID / 256, 256, 0, stream>>>(W, Wt);
    k_gemm1<<<dim3(NN / 32, HID / 64), 128, 0, stream>>>(Xb, Wt, a_edge, hT, s1, s2);
    for (int s = 0; s < ns; s++) {
        int j0 = s * Kstrip;
        k_build<<<NN, 256, 0, stream>>>(adj, s1, s2, P, denom, j0, Kstrip);
        k_gemm2<<<dim3(NN / 32, HID / 64), 128, 0, stream>>>(P, hT, U, j0, Kstrip);
    }
    k_norm<<<NN, 256, 0, stream>>>(U, denom, out);
}